// Round 5
// baseline (179.908 us; speedup 1.0000x reference)
//
#include <hip/hip_runtime.h>

// ISTFT: B=64, FRAMES=512, BINS=513, FFT_LEN=1024, STRIDE=256
// out: (64, 130816) fp32
#define BATCH    64
#define FRAMES   512
#define BINS     513
#define OUT_LEN  130816            // 256*511
#define HOPS_PER_BLOCK 13          // owned output hops; frames needed = 13+3 = 16 waves

__device__ __forceinline__ float2 cadd(float2 a, float2 b){ return make_float2(a.x+b.x, a.y+b.y); }
__device__ __forceinline__ float2 csub(float2 a, float2 b){ return make_float2(a.x-b.x, a.y-b.y); }
__device__ __forceinline__ float2 cmul(float2 a, float2 b){
    return make_float2(a.x*b.x - a.y*b.y, a.x*b.y + a.y*b.x);
}
// LDS pad: +1 float2 every 16
__device__ __forceinline__ int phys(int i){ return i + (i >> 4); }

// 8-point inverse DFT (positive twiddle sign), in place.
__device__ __forceinline__ void bfly8(float2 v[8]) {
    float2 t0 = cadd(v[0], v[4]), t1 = csub(v[0], v[4]);
    float2 t2 = cadd(v[2], v[6]), t3 = csub(v[2], v[6]);
    float2 E0 = cadd(t0, t2), E2 = csub(t0, t2);
    float2 E1 = make_float2(t1.x - t3.y, t1.y + t3.x);   // t1 + i*t3
    float2 E3 = make_float2(t1.x + t3.y, t1.y - t3.x);   // t1 - i*t3
    float2 u0 = cadd(v[1], v[5]), u1 = csub(v[1], v[5]);
    float2 u2 = cadd(v[3], v[7]), u3 = csub(v[3], v[7]);
    float2 O0 = cadd(u0, u2), O2 = csub(u0, u2);
    float2 O1 = make_float2(u1.x - u3.y, u1.y + u3.x);
    float2 O3 = make_float2(u1.x + u3.y, u1.y - u3.x);
    const float C = 0.70710678118654752440f;
    float2 w1 = make_float2(C*(O1.x - O1.y),  C*(O1.x + O1.y));   // W8^1 * O1
    float2 w2 = make_float2(-O2.y, O2.x);                         // i * O2
    float2 w3 = make_float2(-C*(O3.x + O3.y), C*(O3.x - O3.y));   // W8^3 * O3
    v[0] = cadd(E0, O0); v[4] = csub(E0, O0);
    v[1] = cadd(E1, w1); v[5] = csub(E1, w1);
    v[2] = cadd(E2, w2); v[6] = csub(E2, w2);
    v[3] = cadd(E3, w3); v[7] = csub(E3, w3);
}

// Block = 16 waves, wave w computes frame f = u0-1+w wave-private (in-place
// LDS, no barriers inside the FFT), then one barrier + cross-wave gather.
// ALL twiddles + window come from one LDS table tw[k] = e^{2pi i k/1024}:
//   pack   : tw[k]          stage1: tw[2*l*t]       (2lt <= 882, no wrap)
//   stage2 : tw[16*p*t]     window: (0.5 - 0.5*tw[m].x) * 2/(3*1024)
__global__ __launch_bounds__(1024, 8) void istft_kernel(
    const float* __restrict__ re_g, const float* __restrict__ im_g,
    float* __restrict__ out)
{
    __shared__ float2 Xbuf[16][544];   // phys(511) = 542 max
    __shared__ float2 tw[1088];        // phys(1023) = 1086 max

    const int tid  = threadIdx.x;
    const int wave = tid >> 6;
    const int lane = tid & 63;
    const int b    = blockIdx.y;
    const int u0   = blockIdx.x * HOPS_PER_BLOCK;
    const int f    = u0 - 1 + wave;                 // frame this wave computes
    const bool valid = (f >= 0) && (f < FRAMES);

    // twiddle table: ONE sincos per thread for the whole block
    {
        float t = (float)tid * (1.0f/1024.0f);
        tw[phys(tid)] = make_float2(__builtin_amdgcn_cosf(t),
                                    __builtin_amdgcn_sinf(t));
    }
    __syncthreads();   // cheap: every wave reaches this within a few instrs

    float2* Xb = Xbuf[wave];

    if (valid) {
        const long long off = (long long)(b * FRAMES + f) * BINS;
        const float* re = re_g + off;
        const float* im = im_g + off;

        // ---- load + Hermitian pack straight into stage-1 registers ----
        // v[j] = Z[l+64j] (unscaled), Z[k] = S + i*t*D,
        // S = X[k]+conj(X[512-k]), D = X[k]-conj(X[512-k]), t = e^{2pi i k/1024}
        float2 v[8];
        #pragma unroll
        for (int j = 0; j < 8; ++j) {
            int k = lane + 64*j;
            float xar = re[k];
            float xai = (k == 0) ? 0.0f : im[k];         // irfft ignores Im(DC)
            float xcr = re[512 - k];
            float xci = (k == 0) ? 0.0f : im[512 - k];   // Im(Nyquist) ignored
            float Sx = xar + xcr, Sy = xai - xci;
            float Dx = xar - xcr, Dy = xai + xci;
            float2 tk = tw[phys(k)];                     // stride-1: conflict-free
            v[j].x = Sx - tk.x*Dy - tk.y*Dx;
            v[j].y = Sy + tk.x*Dx - tk.y*Dy;
        }

        // ---- 512-pt inverse FFT: 3 x radix-8 Stockham, in-place per wave ----
        // stage 1: v[r]=Z[l+64r] (in regs) -> Xb[8l+t] * e^{2pi i l t/512}
        bfly8(v);
        {
            int basei = phys(8*lane);   // 8l..8l+7 never cross a 16-block: contiguous
            Xb[basei] = v[0];
            #pragma unroll
            for (int t = 1; t < 8; ++t)
                Xb[basei + t] = cmul(v[t], tw[phys(2*lane*t)]);
        }
        // stage 2: read Xb[l+64r] -> write Xb[q+64p+8t] * e^{2pi i p t/64}
        // (same-wave DS ops processed in order; lockstep wave -> no barrier)
        {
            #pragma unroll
            for (int r = 0; r < 8; ++r) v[r] = Xb[phys(lane + 64*r)];
            bfly8(v);
            int p = lane >> 3, q = lane & 7;
            Xb[phys(q + 64*p)] = v[0];
            #pragma unroll
            for (int t = 1; t < 8; ++t)
                Xb[phys(q + 64*p + 8*t)] = cmul(v[t], tw[phys(16*p*t)]);
        }
        // stage 3: read Xb[l+64r] -> write Xb[l+64t], no twiddle
        {
            #pragma unroll
            for (int r = 0; r < 8; ++r) v[r] = Xb[phys(lane + 64*r)];
            bfly8(v);
            #pragma unroll
            for (int t = 0; t < 8; ++t) Xb[phys(lane + 64*t)] = v[t];
        }
    }
    __syncthreads();   // publish frame buffers

    // ---- gather: out[256u+r] = sum_{q=0..3} win[r+256q] * x_{u+2-q}[r+256q] ----
    // x stored interleaved: x[m] = Xbuf[f'-u0+1][phys(m>>1)].{x if m even else y}
    // win[m] = s2 - s2*tw[m].x, s2 = 0.5 * (2/3) * (1/1024)  (irfft scale folded)
    const float s2 = 1.0f / 3072.0f;
    const int nU   = min(HOPS_PER_BLOCK, (OUT_LEN/256) - u0);   // 511 hops total
    const int nOut = nU * 256;
    float* outp = out + (long long)b * OUT_LEN + 256 * u0;
    for (int tl = tid; tl < nOut; tl += 1024) {
        int r  = tl & 255;
        int u  = u0 + (tl >> 8);
        float sum = 0.0f;
        #pragma unroll
        for (int qq = 0; qq < 4; ++qq) {
            int ff = u + 2 - qq;
            if (ff >= 0 && ff < FRAMES) {
                int w  = ff - u0 + 1;              // wave buffer index, 0..15
                int m  = r + 256*qq;
                float2 z = Xbuf[w][phys(m >> 1)];
                float val = (m & 1) ? z.y : z.x;
                float wn = fmaf(-s2, tw[phys(m)].x, s2);
                sum = fmaf(val, wn, sum);
            }
        }
        outp[tl] = sum;
    }
}

extern "C" void kernel_launch(void* const* d_in, const int* in_sizes, int n_in,
                              void* d_out, int out_size, void* d_ws, size_t ws_size,
                              hipStream_t stream) {
    const float* real = (const float*)d_in[0];
    const float* imag = (const float*)d_in[1];
    float* out = (float*)d_out;

    // 511 output hops per row, 13 per block -> 40 blocks per row
    dim3 grid((OUT_LEN/256 + HOPS_PER_BLOCK - 1) / HOPS_PER_BLOCK, BATCH);
    dim3 block(1024);
    istft_kernel<<<grid, block, 0, stream>>>(real, imag, out);
}

// Round 6
// 162.243 us; speedup vs baseline: 1.1089x; 1.1089x over previous
//
#include <hip/hip_runtime.h>

// ISTFT: B=64, FRAMES=512, BINS=513, FFT_LEN=1024, STRIDE=256
// out: (64, 130816) fp32
#define BATCH    64
#define FRAMES   512
#define BINS     513
#define OUT_LEN  130816            // 256*511
#define HOPS_PER_BLOCK 13          // owned output hops; frames needed = 13+3 = 16 waves

__device__ __forceinline__ float2 cadd(float2 a, float2 b){ return make_float2(a.x+b.x, a.y+b.y); }
__device__ __forceinline__ float2 csub(float2 a, float2 b){ return make_float2(a.x-b.x, a.y-b.y); }
__device__ __forceinline__ float2 cmul(float2 a, float2 b){
    return make_float2(a.x*b.x - a.y*b.y, a.x*b.y + a.y*b.x);
}
// e^{2*pi*i*t}, t in REVOLUTIONS, t in [0,1): raw v_sin/v_cos, no range reduction
__device__ __forceinline__ float2 cexp_rev(float t){
    return make_float2(__builtin_amdgcn_cosf(t), __builtin_amdgcn_sinf(t));
}
// LDS pad: +1 float2 every 16
__device__ __forceinline__ int phys(int i){ return i + (i >> 4); }

// 8-point inverse DFT (positive twiddle sign), in place.
__device__ __forceinline__ void bfly8(float2 v[8]) {
    float2 t0 = cadd(v[0], v[4]), t1 = csub(v[0], v[4]);
    float2 t2 = cadd(v[2], v[6]), t3 = csub(v[2], v[6]);
    float2 E0 = cadd(t0, t2), E2 = csub(t0, t2);
    float2 E1 = make_float2(t1.x - t3.y, t1.y + t3.x);   // t1 + i*t3
    float2 E3 = make_float2(t1.x + t3.y, t1.y - t3.x);   // t1 - i*t3
    float2 u0 = cadd(v[1], v[5]), u1 = csub(v[1], v[5]);
    float2 u2 = cadd(v[3], v[7]), u3 = csub(v[3], v[7]);
    float2 O0 = cadd(u0, u2), O2 = csub(u0, u2);
    float2 O1 = make_float2(u1.x - u3.y, u1.y + u3.x);
    float2 O3 = make_float2(u1.x + u3.y, u1.y - u3.x);
    const float C = 0.70710678118654752440f;
    float2 w1 = make_float2(C*(O1.x - O1.y),  C*(O1.x + O1.y));   // W8^1 * O1
    float2 w2 = make_float2(-O2.y, O2.x);                         // i * O2
    float2 w3 = make_float2(-C*(O3.x + O3.y), C*(O3.x - O3.y));   // W8^3 * O3
    v[0] = cadd(E0, O0); v[4] = csub(E0, O0);
    v[1] = cadd(E1, w1); v[5] = csub(E1, w1);
    v[2] = cadd(E2, w2); v[6] = csub(E2, w2);
    v[3] = cadd(E3, w3); v[7] = csub(E3, w3);
}

// Block = 16 waves, wave w computes frame f = u0-1+w fully wave-private
// (registers + its own in-place LDS buffer, ZERO barriers), then one
// __syncthreads and a cross-wave gather with paired b64 loads/stores.
__global__ __launch_bounds__(1024, 8) void istft_kernel(
    const float* __restrict__ re_g, const float* __restrict__ im_g,
    float* __restrict__ out)
{
    __shared__ float2 Xbuf[16][544];            // phys(511) = 542 max
    __shared__ __align__(16) float win[1024];   // hann/1.5/1024 (irfft scale folded)

    const int tid  = threadIdx.x;
    const int wave = tid >> 6;
    const int lane = tid & 63;
    const int b    = blockIdx.y;
    const int u0   = blockIdx.x * HOPS_PER_BLOCK;
    const int f    = u0 - 1 + wave;                 // frame this wave computes
    const bool valid = (f >= 0) && (f < FRAMES);

    // win[m] = (0.5 - 0.5 cos(2 pi m/1024)) * (2/3) * (1/1024)
    win[tid] = (0.5f - 0.5f * __builtin_amdgcn_cosf((float)tid * (1.0f/1024.0f)))
               * (2.0f / 3.0f / 1024.0f);

    float2* Xb = Xbuf[wave];

    if (valid) {
        const long long off = (long long)(b * FRAMES + f) * BINS;
        const float* re = re_g + off;
        const float* im = im_g + off;

        // ---- load + Hermitian pack straight into stage-1 registers ----
        // v[j] = Z[l+64j] (unscaled), Z[k] = S + i*t*D,
        // S = X[k]+conj(X[512-k]), D = X[k]-conj(X[512-k]), t = e^{2pi i k/1024}
        const float a0 = (float)lane * (1.0f/1024.0f);
        float2 v[8];
        #pragma unroll
        for (int j = 0; j < 8; ++j) {
            int k = lane + 64*j;
            float xar = re[k];
            float xai = (k == 0) ? 0.0f : im[k];         // irfft ignores Im(DC)
            float xcr = re[512 - k];
            float xci = (k == 0) ? 0.0f : im[512 - k];   // Im(Nyquist) ignored
            float Sx = xar + xcr, Sy = xai - xci;
            float Dx = xar - xcr, Dy = xai + xci;
            float2 tk = cexp_rev(a0 + (float)j * (1.0f/16.0f));  // exact dyadic arg
            v[j].x = Sx - tk.x*Dy - tk.y*Dx;
            v[j].y = Sy + tk.x*Dx - tk.y*Dy;
        }

        // ---- 512-pt inverse FFT: 3 x radix-8 Stockham, in-place per wave ----
        // stage 1: v[r]=Z[l+64r] (in regs) -> Xb[8l+t] * e^{2pi i l t/512}
        bfly8(v);
        {
            const float lt = (float)lane * (1.0f/512.0f);
            int basei = phys(8*lane);                  // = 8l+(l>>1); t contiguous
            Xb[basei] = v[0];
            #pragma unroll
            for (int t = 1; t < 8; ++t)
                Xb[basei + t] = cmul(v[t], cexp_rev((float)t * lt));
        }
        // stage 2: read Xb[l+64r] -> write Xb[q+64p+8t] * e^{2pi i p t/64}
        // (same-wave DS ops processed in order; lockstep wave -> no barrier)
        {
            #pragma unroll
            for (int r = 0; r < 8; ++r) v[r] = Xb[phys(lane + 64*r)];
            bfly8(v);
            int p = lane >> 3, q = lane & 7;
            const float pf = (float)p * (1.0f/64.0f);
            Xb[phys(q + 64*p)] = v[0];
            #pragma unroll
            for (int t = 1; t < 8; ++t)
                Xb[phys(q + 64*p + 8*t)] = cmul(v[t], cexp_rev((float)t * pf));
        }
        // stage 3: read Xb[l+64r] -> write Xb[l+64t], no twiddle
        {
            #pragma unroll
            for (int r = 0; r < 8; ++r) v[r] = Xb[phys(lane + 64*r)];
            bfly8(v);
            #pragma unroll
            for (int t = 0; t < 8; ++t) Xb[phys(lane + 64*t)] = v[t];
        }
    }
    __syncthreads();   // the ONLY barrier: publish frame buffers + win table

    // ---- gather, paired: each thread makes outputs (2pi, 2pi+1) ----
    // out[256u+r] = sum_q win[r+256q] * x_{u+2-q}[r+256q];  with r even, the
    // Xbuf float2 at phys(m>>1) provides BOTH x[m] and x[m+1], and win[m..m+1]
    // reads as one aligned float2 -> half the DS ops, dwordx2 stores.
    const int nU    = min(HOPS_PER_BLOCK, (OUT_LEN/256) - u0);   // 511 hops total
    const int nPair = nU * 128;
    float2* outp2 = (float2*)(out + (long long)b * OUT_LEN + 256 * u0);
    const float2* win2 = (const float2*)win;
    for (int pi = tid; pi < nPair; pi += 1024) {
        int o0 = pi * 2;
        int r  = o0 & 255;                 // even
        int u  = u0 + (o0 >> 8);
        float s0 = 0.0f, s1 = 0.0f;
        #pragma unroll
        for (int qq = 0; qq < 4; ++qq) {
            int ff = u + 2 - qq;
            if (ff >= 0 && ff < FRAMES) {
                int w = ff - u0 + 1;       // wave buffer index, 0..15
                int h = (r >> 1) + 128*qq; // == m>>1, m = r + 256q (even)
                float2 z  = Xbuf[w][phys(h)];
                float2 wn = win2[h & 511]; // win index m>>1; m<1024 so h<512
                s0 = fmaf(z.x, wn.x, s0);
                s1 = fmaf(z.y, wn.y, s1);
            }
        }
        outp2[pi] = make_float2(s0, s1);
    }
}

extern "C" void kernel_launch(void* const* d_in, const int* in_sizes, int n_in,
                              void* d_out, int out_size, void* d_ws, size_t ws_size,
                              hipStream_t stream) {
    const float* real = (const float*)d_in[0];
    const float* imag = (const float*)d_in[1];
    float* out = (float*)d_out;

    // 511 output hops per row, 13 per block -> 40 blocks per row
    dim3 grid((OUT_LEN/256 + HOPS_PER_BLOCK - 1) / HOPS_PER_BLOCK, BATCH);
    dim3 block(1024);
    istft_kernel<<<grid, block, 0, stream>>>(real, imag, out);
}